// Round 20
// baseline (66.594 us; speedup 1.0000x reference)
//
#include <hip/hip_runtime.h>
#include <hip/hip_bf16.h>
#include <math.h>

// Problem constants
constexpr int B = 4, S = 4096, N = 16, D = 64, M = 4;
constexpr int SND = S * N * D;      // b stride for q/k/v (floats)
constexpr int ND  = N * D;          // s stride (floats)
constexpr int DD  = D * D;          // 4096
constexpr int NCH = 16;             // k1 chunks per bn
constexpr int SPB = S / NCH;        // 256 s per block (8 steps of 32 rows)

typedef __attribute__((ext_vector_type(8))) short bf16x8;
typedef __attribute__((ext_vector_type(4))) float f32x4;
typedef unsigned short u16;
typedef unsigned int u32;

__device__ inline u16 f2bf(float x) {
  __hip_bfloat16 h = __float2bfloat16(x);   // RNE
  return __builtin_bit_cast(u16, h);
}

// ---------------------------------------------------------------------------
// Kernel 1: part[bn][ch] = sum_{s in chunk} K[s,:]^T ⊗ V[s,:]  via MFMA (bf16).
// r9 RERUN WITH THE DISEASE FIXED: no LDS, no barriers, scalar global gather
// of MFMA fragments — but wave owns a 16x64 C-strip so acc = 16 VGPRs (r9
// died with 64 acc VGPRs -> VGPR_Count=64 total -> serialized loads). The
// consumer is register-only (cvt+MFMA), the exact pattern the r11 probe
// proved sustains deep MLP (~6.5 TB/s on this geometry).
// Per 32-row step, per thread: 8 K + 32 V independent dword loads.
//   Per instruction across the wave: 4 rows x 64 B fully-used line segments.
//   K columns are disjoint across waves (w*16); V is wave-redundant 4x
//   (same block -> same CU -> L1 absorbs).
// Fragment values & C mapping identical to the r6/r10/r16 verified path:
//   af[j] = K[8lg+j][16w+lr], bq[ni][j] = V[8lg+j][16ni+lr]
//   C: p[(16w + 4lg + ri)*64 + 16ni + lr] = acc[ni][ri]
// grid = (64 bn, 16 ch), block = 256 (4 waves) -> 1024 blocks, 4/CU.
// ---------------------------------------------------------------------------
__global__ __launch_bounds__(256) void k1_partials(const float* __restrict__ kg,
                                                   const float* __restrict__ vg,
                                                   u16* __restrict__ part) {
  const int t = threadIdx.x, w = t >> 6, l = t & 63;
  const int lr = l & 15, lg = l >> 4;
  const int bn = blockIdx.x, ch = blockIdx.y;
  const int b = bn >> 4, n = bn & 15;

  const size_t base = (size_t)b * SND + (size_t)n * D + (size_t)ch * SPB * ND;
  const float* kp = kg + base + 16 * w + lr;   // wave's K column + lane col
  const float* vp = vg + base + lr;            // V lane col (ni via +16*ni)

  f32x4 acc[4];
#pragma unroll
  for (int i = 0; i < 4; ++i) acc[i] = (f32x4)0.f;

#pragma unroll
  for (int st = 0; st < 8; ++st) {
    // ---- gather: 40 independent dword loads (deep MLP, no LDS) ----
    float kd[8], vd[8][4];
#pragma unroll
    for (int j = 0; j < 8; ++j) {
      const size_t ro = ((size_t)st * 32 + 8 * lg + j) * ND;
      kd[j]    = kp[ro];
      vd[j][0] = vp[ro];
      vd[j][1] = vp[ro + 16];
      vd[j][2] = vp[ro + 32];
      vd[j][3] = vp[ro + 48];
    }
    // ---- convert + 4 MFMA ----
    bf16x8 af, bq[4];
#pragma unroll
    for (int j = 0; j < 8; ++j) af[j] = (short)f2bf(kd[j]);
#pragma unroll
    for (int ni = 0; ni < 4; ++ni)
#pragma unroll
      for (int j = 0; j < 8; ++j) bq[ni][j] = (short)f2bf(vd[j][ni]);
#pragma unroll
    for (int ni = 0; ni < 4; ++ni)
      acc[ni] = __builtin_amdgcn_mfma_f32_16x16x32_bf16(af, bq[ni],
                                                        acc[ni], 0, 0, 0);
  }

  // bf16 partial store (verified C mapping): rows 16w..16w+15
  u16* p = part + ((size_t)bn * NCH + ch) * DD;
#pragma unroll
  for (int ni = 0; ni < 4; ++ni)
#pragma unroll
    for (int ri = 0; ri < 4; ++ri)
      p[(16 * w + 4 * lg + ri) * 64 + 16 * ni + lr] = f2bf(acc[ni][ri]);
}

// ---------------------------------------------------------------------------
// Kernel 2: Meff combine (part is bf16, NCH=16). Emits bf16 meffT[bn][v][k].
// grid = (64, 16), block = 256.
// ---------------------------------------------------------------------------
__global__ __launch_bounds__(256) void k2_combine(const u16* __restrict__ part,
                                                  const float* __restrict__ memg,
                                                  const float* __restrict__ decay,
                                                  const float* __restrict__ gatew,
                                                  u16* __restrict__ meffT) {
  const int t = threadIdx.x;
  const int bn = blockIdx.x;
  const int b = bn >> 4, n = bn & 15;
  const int kv = blockIdx.y * 256 + t;
  const int k = kv >> 6, v = kv & 63;

  float gw[M], df[M];
#pragma unroll
  for (int m = 0; m < M; ++m) { gw[m] = gatew[m]; df[m] = decay[m]; }
  const float mx = fmaxf(fmaxf(gw[0], gw[1]), fmaxf(gw[2], gw[3]));
  float e[M], esum = 0.f;
#pragma unroll
  for (int m = 0; m < M; ++m) { e[m] = expf(gw[m] - mx); esum += e[m]; }
  float wgt[M], cc = 0.f;
#pragma unroll
  for (int m = 0; m < M; ++m) {
    const float g = e[m] / esum;
    const float sg = 1.f / (1.f + expf(-df[m]));
    wgt[m] = g * sg;
    cc += g * (1.f - sg);
  }

  const u16* pb = part + (size_t)bn * NCH * DD + kv;
  float ni = 0.f;
#pragma unroll 8
  for (int ch = 0; ch < NCH; ++ch) {
    __hip_bfloat16 h = __builtin_bit_cast(__hip_bfloat16, pb[(size_t)ch * DD]);
    ni += __bfloat162float(h);
  }
  float a = cc * ni;
#pragma unroll
  for (int m = 0; m < M; ++m)
    a += wgt[m] * memg[(((size_t)b * M + m) * N + n) * DD + kv];

  meffT[(size_t)bn * DD + v * 64 + k] = f2bf(a);
}

// ---------------------------------------------------------------------------
// Kernel 3: out[s,v] = q[s,:] @ Meff  via MFMA, LDS-free, free-running.
// grid = (64 bn, 16), block = 256 (4 waves); wave handles 64 s-rows x 64 v.
// ---------------------------------------------------------------------------
__global__ __launch_bounds__(256, 4) void k3_out(const float* __restrict__ qg,
                                                 const u16* __restrict__ meffT,
                                                 float* __restrict__ outg) {
  const int t = threadIdx.x, w = t >> 6, l = t & 63;
  const int lr = l & 15, lg = l >> 4;
  const int bn = blockIdx.x;
  const int b = bn >> 4, n = bn & 15;
  const int s0 = blockIdx.y * 256 + w * 64;

  const u16* mb = meffT + (size_t)bn * DD;
  bf16x8 bfr[4][2];
#pragma unroll
  for (int ni = 0; ni < 4; ++ni)
#pragma unroll
    for (int ks = 0; ks < 2; ++ks)
      bfr[ni][ks] = *(const bf16x8*)(mb + (16 * ni + lr) * 64 + 32 * ks + 8 * lg);

  f32x4 acc[4][4];
#pragma unroll
  for (int i = 0; i < 4; ++i)
#pragma unroll
    for (int j = 0; j < 4; ++j) acc[i][j] = (f32x4)0.f;

  const size_t qbase = (size_t)b * SND + (size_t)n * D;

#pragma unroll
  for (int mi = 0; mi < 4; ++mi) {
    const float* qr = qg + qbase + (size_t)(s0 + 16 * mi + lr) * ND + 8 * lg;
#pragma unroll
    for (int ks = 0; ks < 2; ++ks) {
      float qa[8];
      *(float4*)&qa[0] = *(const float4*)(qr + 32 * ks);
      *(float4*)&qa[4] = *(const float4*)(qr + 32 * ks + 4);
      bf16x8 a;
#pragma unroll
      for (int j = 0; j < 8; ++j) a[j] = (short)f2bf(qa[j]);
#pragma unroll
      for (int ni = 0; ni < 4; ++ni)
        acc[mi][ni] = __builtin_amdgcn_mfma_f32_16x16x32_bf16(a, bfr[ni][ks],
                                                              acc[mi][ni], 0, 0, 0);
    }
  }

#pragma unroll
  for (int mi = 0; mi < 4; ++mi)
#pragma unroll
    for (int ni = 0; ni < 4; ++ni)
#pragma unroll
      for (int ri = 0; ri < 4; ++ri)
        outg[qbase + (size_t)(s0 + 16 * mi + 4 * lg + ri) * ND + 16 * ni + lr] =
            acc[mi][ni][ri];
}

// ---------------------------------------------------------------------------
extern "C" void kernel_launch(void* const* d_in, const int* in_sizes, int n_in,
                              void* d_out, int out_size, void* d_ws, size_t ws_size,
                              hipStream_t stream) {
  const float* q     = (const float*)d_in[0];
  const float* k     = (const float*)d_in[1];
  const float* v     = (const float*)d_in[2];
  const float* memg  = (const float*)d_in[3];
  const float* decay = (const float*)d_in[4];
  const float* gatew = (const float*)d_in[5];
  float* out = (float*)d_out;

  u16* meffT = (u16*)d_ws;                            // 512 KB
  const size_t meffT_bytes = (size_t)64 * DD * sizeof(u16);
  u16* part = (u16*)((char*)d_ws + meffT_bytes);      // 8 MB bf16 partials

  hipLaunchKernelGGL(k1_partials, dim3(64, NCH), dim3(256), 0, stream,
                     k, v, part);
  hipLaunchKernelGGL(k2_combine, dim3(64, 16), dim3(256), 0, stream,
                     part, memg, decay, gatew, meffT);
  hipLaunchKernelGGL(k3_out, dim3(64, 16), dim3(256), 0, stream,
                     q, meffT, out);
}